// Round 3
// baseline (1518.301 us; speedup 1.0000x reference)
//
#include <hip/hip_runtime.h>
#include <cstdint>

#define NU 100000
#define NI 100000
#define NN 200000
#define NE 3200000
#define TXT 768
#define DD 32
#define WT2_S 386      // uint (bf16-pair) stride for packed W1^T rows
#define NRANGE 8
#define ROWS_PER_RANGE (NN / NRANGE)   // 25000
#define NBJ 313        // blocks per range for ranged kernels

__device__ __forceinline__ float lrelu(float x) { return x >= 0.f ? x : 0.01f * x; }
__device__ __forceinline__ unsigned bf16rne(float f) {
    unsigned u = __float_as_uint(f);
    return (u + 0x7fffu + ((u >> 16) & 1u)) >> 16;
}
__device__ __forceinline__ float bl(unsigned u){ return __uint_as_float(u << 16); }
__device__ __forceinline__ float bh(unsigned u){ return __uint_as_float(u & 0xffff0000u); }

// ---------------------------------------------------------------------------
// Copy pretrained 16-dim embeddings into ego[:,0:16] and out[:,0:16]
// ---------------------------------------------------------------------------
__global__ void copy_emb_kernel(const float* __restrict__ uemb,
                                const float* __restrict__ iemb,
                                float* __restrict__ ego,
                                float* __restrict__ outp)
{
    int idx = blockIdx.x * blockDim.x + threadIdx.x;
    if (idx >= NN * 4) return;
    int n = idx >> 2, q = idx & 3;
    float4 v;
    if (n < NU) v = ((const float4*)uemb)[(size_t)n * 4 + q];
    else        v = ((const float4*)iemb)[(size_t)(n - NU) * 4 + q];
    ((float4*)ego)[(size_t)n * 8 + q]   = v;
    ((float4*)outp)[(size_t)n * 32 + q] = v;
}

// ---------------------------------------------------------------------------
// created = relu(X @ W1) @ W2 ; writes ego[:,16:32] and out[:,16:32]
// W1^T packed bf16 in LDS (49.4 KB -> 2 blocks/CU, 16 waves/CU).
// Thread (cg=t&7, r=t>>3): 4 h-cols, 2 rows. shfl butterfly for 2nd matmul.
// ---------------------------------------------------------------------------
__global__ __launch_bounds__(512, 4) void mlp_kernel(
    const float* __restrict__ X,    // nrows x 768
    const float* __restrict__ W1,   // 768 x 32
    const float* __restrict__ W2,   // 32 x 16
    float* __restrict__ ego,
    float* __restrict__ outp,
    int nrows, int node_base)
{
    __shared__ unsigned Wtp[DD * WT2_S];   // Wtp[c*386+p] = pack(W1[2p][c],W1[2p+1][c])
    __shared__ float W2s[DD * 17];

    for (int i = threadIdx.x; i < 384 * DD; i += 512) {
        int p = i >> 5;
        int c = i & 31;
        unsigned lo = bf16rne(W1[(2 * p) * DD + c]);
        unsigned hi = bf16rne(W1[(2 * p + 1) * DD + c]);
        Wtp[c * WT2_S + p] = lo | (hi << 16);
    }
    for (int i = threadIdx.x; i < DD * 16; i += 512)
        W2s[(i >> 4) * 17 + (i & 15)] = W2[i];
    __syncthreads();

    const int cg = threadIdx.x & 7;
    const int r  = threadIdx.x >> 3;
    const unsigned* wp0 = &Wtp[(cg * 4 + 0) * WT2_S];
    const unsigned* wp1 = &Wtp[(cg * 4 + 1) * WT2_S];
    const unsigned* wp2 = &Wtp[(cg * 4 + 2) * WT2_S];
    const unsigned* wp3 = &Wtp[(cg * 4 + 3) * WT2_S];

    const int ntiles = (nrows + 127) / 128;
    for (int tile = blockIdx.x; tile < ntiles; tile += gridDim.x) {
        const int row0 = tile * 128 + r;
        const int row1 = row0 + 64;
        const bool ok0 = row0 < nrows, ok1 = row1 < nrows;
        const float* x0 = X + (size_t)(ok0 ? row0 : 0) * TXT;
        const float* x1 = X + (size_t)(ok1 ? row1 : 0) * TXT;

        float a[2][4] = {{0.f,0.f,0.f,0.f},{0.f,0.f,0.f,0.f}};
        #pragma unroll 4
        for (int k = 0; k < TXT; k += 4) {
            const float4 xa = *(const float4*)(x0 + k);
            const float4 xb = *(const float4*)(x1 + k);
            const int p = k >> 1;
            const uint2 u0 = *(const uint2*)(wp0 + p);
            const uint2 u1 = *(const uint2*)(wp1 + p);
            const uint2 u2 = *(const uint2*)(wp2 + p);
            const uint2 u3 = *(const uint2*)(wp3 + p);
            float w00 = bl(u0.x), w01 = bh(u0.x), w02 = bl(u0.y), w03 = bh(u0.y);
            float w10 = bl(u1.x), w11 = bh(u1.x), w12 = bl(u1.y), w13 = bh(u1.y);
            float w20 = bl(u2.x), w21 = bh(u2.x), w22 = bl(u2.y), w23 = bh(u2.y);
            float w30 = bl(u3.x), w31 = bh(u3.x), w32 = bl(u3.y), w33 = bh(u3.y);
            a[0][0] += xa.x*w00 + xa.y*w01 + xa.z*w02 + xa.w*w03;
            a[0][1] += xa.x*w10 + xa.y*w11 + xa.z*w12 + xa.w*w13;
            a[0][2] += xa.x*w20 + xa.y*w21 + xa.z*w22 + xa.w*w23;
            a[0][3] += xa.x*w30 + xa.y*w31 + xa.z*w32 + xa.w*w33;
            a[1][0] += xb.x*w00 + xb.y*w01 + xb.z*w02 + xb.w*w03;
            a[1][1] += xb.x*w10 + xb.y*w11 + xb.z*w12 + xb.w*w13;
            a[1][2] += xb.x*w20 + xb.y*w21 + xb.z*w22 + xb.w*w23;
            a[1][3] += xb.x*w30 + xb.y*w31 + xb.z*w32 + xb.w*w33;
        }

        #pragma unroll
        for (int rr = 0; rr < 2; ++rr) {
            float h0 = fmaxf(a[rr][0], 0.f), h1 = fmaxf(a[rr][1], 0.f);
            float h2 = fmaxf(a[rr][2], 0.f), h3 = fmaxf(a[rr][3], 0.f);
            float p[16];
            #pragma unroll
            for (int j = 0; j < 16; ++j)
                p[j] = h0 * W2s[(cg*4+0)*17 + j] + h1 * W2s[(cg*4+1)*17 + j]
                     + h2 * W2s[(cg*4+2)*17 + j] + h3 * W2s[(cg*4+3)*17 + j];
            #pragma unroll
            for (int m = 1; m <= 4; m <<= 1) {
                #pragma unroll
                for (int j = 0; j < 16; ++j) p[j] += __shfl_xor(p[j], m, 64);
            }
            const int row = rr ? row1 : row0;
            const bool ok = rr ? ok1 : ok0;
            if (ok && cg < 4) {
                const int node = node_base + row;
                float4 v = make_float4(p[cg*4+0], p[cg*4+1], p[cg*4+2], p[cg*4+3]);
                *(float4*)(ego  + (size_t)node * 32  + 16 + cg * 4) = v;
                *(float4*)(outp + (size_t)node * 128 + 16 + cg * 4) = v;
            }
        }
    }
}

// ---------------------------------------------------------------------------
// XCD-range-partitioned CSR build. Block b handles rows in range (b&7);
// round-robin blockIdx->XCD keeps each range's atomics/stores in ONE L2.
// ---------------------------------------------------------------------------
__global__ __launch_bounds__(256) void count_ranged_kernel(const int* __restrict__ erow,
                                                           int* __restrict__ cnt)
{
    const int rlo = (blockIdx.x & 7) * ROWS_PER_RANGE;
    const int rhi = rlo + ROWS_PER_RANGE;
    const int bj  = blockIdx.x >> 3;
    const int4* e4 = (const int4*)erow;
    for (int c = bj * 256 + threadIdx.x; c < NE / 4; c += NBJ * 256) {
        int4 v = e4[c];
        if (v.x >= rlo && v.x < rhi) atomicAdd(&cnt[v.x], 1);
        if (v.y >= rlo && v.y < rhi) atomicAdd(&cnt[v.y], 1);
        if (v.z >= rlo && v.z < rhi) atomicAdd(&cnt[v.z], 1);
        if (v.w >= rlo && v.w < rhi) atomicAdd(&cnt[v.w], 1);
    }
}

__global__ __launch_bounds__(256) void scan_blk_kernel(const int* __restrict__ cnt,
                                                       int* __restrict__ rp,
                                                       int* __restrict__ bsum)
{
    __shared__ int ts[256];
    const int tid = threadIdx.x;
    const int base = blockIdx.x * 1024 + tid * 4;
    int v0 = (base + 0 < NN) ? cnt[base + 0] : 0;
    int v1 = (base + 1 < NN) ? cnt[base + 1] : 0;
    int v2 = (base + 2 < NN) ? cnt[base + 2] : 0;
    int v3 = (base + 3 < NN) ? cnt[base + 3] : 0;
    int s = v0 + v1 + v2 + v3;
    ts[tid] = s;
    __syncthreads();
    for (int off = 1; off < 256; off <<= 1) {
        int t = (tid >= off) ? ts[tid - off] : 0;
        __syncthreads();
        ts[tid] += t;
        __syncthreads();
    }
    int excl = ts[tid] - s;
    if (base + 0 < NN) rp[base + 0] = excl;
    if (base + 1 < NN) rp[base + 1] = excl + v0;
    if (base + 2 < NN) rp[base + 2] = excl + v0 + v1;
    if (base + 3 < NN) rp[base + 3] = excl + v0 + v1 + v2;
    if (tid == 255) bsum[blockIdx.x] = ts[255];
}

__global__ __launch_bounds__(256) void scan_bsum_kernel(int* __restrict__ bsum, int nblk)
{
    __shared__ int ts[256];
    const int tid = threadIdx.x;
    int v = (tid < nblk) ? bsum[tid] : 0;
    ts[tid] = v;
    __syncthreads();
    for (int off = 1; off < 256; off <<= 1) {
        int t = (tid >= off) ? ts[tid - off] : 0;
        __syncthreads();
        ts[tid] += t;
        __syncthreads();
    }
    if (tid < nblk) bsum[tid] = ts[tid] - v;
}

__global__ __launch_bounds__(256) void add_off_kernel(int* __restrict__ rp,
                                                      const int* __restrict__ bsum,
                                                      int* __restrict__ cur)
{
    int i = blockIdx.x * 256 + threadIdx.x;
    if (i < NN) {
        int v = rp[i] + bsum[i >> 10];
        rp[i] = v;
        cur[i] = v;
    }
    if (i == 0) rp[NN] = NE;
}

__global__ __launch_bounds__(256) void fill_ranged_kernel(const int* __restrict__ erow,
                                                          const int* __restrict__ ecol,
                                                          const float* __restrict__ eval,
                                                          int* __restrict__ cur,
                                                          uint2* __restrict__ recs)
{
    const int rlo = (blockIdx.x & 7) * ROWS_PER_RANGE;
    const int rhi = rlo + ROWS_PER_RANGE;
    const int bj  = blockIdx.x >> 3;
    const int4* e4 = (const int4*)erow;
    for (int c = bj * 256 + threadIdx.x; c < NE / 4; c += NBJ * 256) {
        int4 v = e4[c];
        int base = c * 4;
        if (v.x >= rlo && v.x < rhi) {
            int pos = atomicAdd(&cur[v.x], 1);
            recs[pos] = make_uint2((unsigned)ecol[base+0], __float_as_uint(eval[base+0]));
        }
        if (v.y >= rlo && v.y < rhi) {
            int pos = atomicAdd(&cur[v.y], 1);
            recs[pos] = make_uint2((unsigned)ecol[base+1], __float_as_uint(eval[base+1]));
        }
        if (v.z >= rlo && v.z < rhi) {
            int pos = atomicAdd(&cur[v.z], 1);
            recs[pos] = make_uint2((unsigned)ecol[base+2], __float_as_uint(eval[base+2]));
        }
        if (v.w >= rlo && v.w < rhi) {
            int pos = atomicAdd(&cur[v.w], 1);
            recs[pos] = make_uint2((unsigned)ecol[base+3], __float_as_uint(eval[base+3]));
        }
    }
}

// ---------------------------------------------------------------------------
// Fused pull + update. Block = 8 nodes, thread (r=t>>5, j=t&31).
// Gathers read egoIn; result written to egoOut (double-buffered: no race).
// ---------------------------------------------------------------------------
__global__ __launch_bounds__(256) void pull_update_kernel(
    const int* __restrict__ rp, const uint2* __restrict__ recs,
    const float* __restrict__ egoIn, float* __restrict__ egoOut,
    float* __restrict__ outp,
    const float* __restrict__ gcW, const float* __restrict__ gcb,
    const float* __restrict__ biW, const float* __restrict__ bib, int l)
{
    __shared__ float WgT[DD * 36];   // WgT[j*36+k] = gc_W[l][k][j]
    __shared__ float WbT[DD * 36];
    __shared__ float sS[8][36];
    __shared__ float eS[8][36];

    const int tid = threadIdx.x;
    for (int i = tid; i < 1024; i += 256) {
        int k = i >> 5, j = i & 31;
        WgT[j * 36 + k] = gcW[l * 1024 + i];
        WbT[j * 36 + k] = biW[l * 1024 + i];
    }

    const int r = tid >> 5;
    const int j = tid & 31;
    const int node = blockIdx.x * 8 + r;
    const int start = rp[node], end = rp[node + 1];

    float a0 = 0.f, a1 = 0.f;
    int e = start;
    for (; e + 1 < end; e += 2) {
        uint2 r0 = recs[e], r1 = recs[e + 1];
        float v0 = egoIn[(size_t)r0.x * 32 + j];
        float v1 = egoIn[(size_t)r1.x * 32 + j];
        a0 += __uint_as_float(r0.y) * v0;
        a1 += __uint_as_float(r1.y) * v1;
    }
    if (e < end) {
        uint2 r0 = recs[e];
        a0 += __uint_as_float(r0.y) * egoIn[(size_t)r0.x * 32 + j];
    }
    float s = a0 + a1;
    sS[r][j] = s;
    eS[r][j] = s * egoIn[(size_t)node * 32 + j];
    __syncthreads();

    float A = gcb[l * 32 + j];
    float B = bib[l * 32 + j];
    const float* wg = &WgT[j * 36];
    const float* wb = &WbT[j * 36];
    #pragma unroll
    for (int q = 0; q < 8; ++q) {
        float4 sv = *(const float4*)&sS[r][q * 4];
        float4 ev = *(const float4*)&eS[r][q * 4];
        float4 g  = *(const float4*)(wg + q * 4);
        float4 b  = *(const float4*)(wb + q * 4);
        A += sv.x*g.x + sv.y*g.y + sv.z*g.z + sv.w*g.w;
        B += ev.x*b.x + ev.y*b.y + ev.z*b.z + ev.w*b.w;
    }
    float v = lrelu(A) + lrelu(B);
    float ss = v * v;
    #pragma unroll
    for (int m = 1; m <= 16; m <<= 1) ss += __shfl_xor(ss, m, 64);
    float inv = 1.0f / fmaxf(sqrtf(ss), 1e-12f);

    egoOut[(size_t)node * 32 + j] = v;
    outp[(size_t)node * 128 + (size_t)(l + 1) * 32 + j] = v * inv;
}

// ---------------------------------------------------------------------------
// Legacy fallback (scatter + separate update) if workspace too small
// ---------------------------------------------------------------------------
__global__ __launch_bounds__(256) void scatter_kernel(
    const int* __restrict__ erow, const int* __restrict__ ecol,
    const float* __restrict__ eval, const float* __restrict__ ego,
    float* __restrict__ side)
{
    int i = blockIdx.x * 256 + threadIdx.x;
    if (i >= NE * 8) return;
    int e = i >> 3, q = i & 7;
    int rI = erow[e];
    int c  = ecol[e];
    float a = eval[e];
    float4 v = ((const float4*)ego)[(size_t)c * 8 + q];
    float* dst = side + (size_t)rI * 32 + q * 4;
    atomicAdd(dst + 0, a * v.x);
    atomicAdd(dst + 1, a * v.y);
    atomicAdd(dst + 2, a * v.z);
    atomicAdd(dst + 3, a * v.w);
}

__global__ __launch_bounds__(256) void update_kernel(
    const float* __restrict__ side, float* __restrict__ ego,
    float* __restrict__ outp,
    const float* __restrict__ gcW, const float* __restrict__ gcb,
    const float* __restrict__ biW, const float* __restrict__ bib, int l)
{
    int n = blockIdx.x * 256 + threadIdx.x;
    if (n >= NN) return;
    float s[32], e[32];
    const float4* s4 = (const float4*)side + (size_t)n * 8;
    const float4* e4 = (const float4*)ego  + (size_t)n * 8;
    #pragma unroll
    for (int q = 0; q < 8; ++q) {
        float4 v = s4[q];
        s[q*4+0]=v.x; s[q*4+1]=v.y; s[q*4+2]=v.z; s[q*4+3]=v.w;
        float4 w = e4[q];
        e[q*4+0]=w.x; e[q*4+1]=w.y; e[q*4+2]=w.z; e[q*4+3]=w.w;
    }
    #pragma unroll
    for (int k = 0; k < 32; ++k) e[k] *= s[k];
    const float* Wg = gcW + (size_t)l * 1024;
    const float* Wb = biW + (size_t)l * 1024;
    float A[32];
    #pragma unroll
    for (int j = 0; j < 32; ++j) A[j] = gcb[l * 32 + j];
    #pragma unroll 4
    for (int k = 0; k < 32; ++k) {
        float sk = s[k];
        #pragma unroll
        for (int j = 0; j < 32; ++j) A[j] += sk * Wg[k * 32 + j];
    }
    #pragma unroll
    for (int j = 0; j < 32; ++j) A[j] = lrelu(A[j]);
    float B[32];
    #pragma unroll
    for (int j = 0; j < 32; ++j) B[j] = bib[l * 32 + j];
    #pragma unroll 4
    for (int k = 0; k < 32; ++k) {
        float pk = e[k];
        #pragma unroll
        for (int j = 0; j < 32; ++j) B[j] += pk * Wb[k * 32 + j];
    }
    float ss = 0.f;
    #pragma unroll
    for (int j = 0; j < 32; ++j) {
        float v = A[j] + lrelu(B[j]);
        A[j] = v;
        ss += v * v;
    }
    float inv = 1.0f / fmaxf(sqrtf(ss), 1e-12f);
    float4* egod = (float4*)(ego + (size_t)n * 32);
    float4* outd = (float4*)(outp + (size_t)n * 128 + (size_t)(l + 1) * 32);
    #pragma unroll
    for (int q = 0; q < 8; ++q) {
        float4 v = make_float4(A[q*4+0], A[q*4+1], A[q*4+2], A[q*4+3]);
        egod[q] = v;
        float4 w = make_float4(v.x*inv, v.y*inv, v.z*inv, v.w*inv);
        outd[q] = w;
    }
}

// ---------------------------------------------------------------------------
extern "C" void kernel_launch(void* const* d_in, const int* in_sizes, int n_in,
                              void* d_out, int out_size, void* d_ws, size_t ws_size,
                              hipStream_t stream)
{
    const int*   erow = (const int*)d_in[0];
    const int*   ecol = (const int*)d_in[1];
    const float* evalp = (const float*)d_in[2];
    const float* une  = (const float*)d_in[3];
    const float* se   = (const float*)d_in[4];
    const float* uemb = (const float*)d_in[5];
    const float* iemb = (const float*)d_in[6];
    const float* ueW1 = (const float*)d_in[7];
    const float* ueW2 = (const float*)d_in[8];
    const float* ieW1 = (const float*)d_in[9];
    const float* ieW2 = (const float*)d_in[10];
    const float* gcW  = (const float*)d_in[11];
    const float* gcb  = (const float*)d_in[12];
    const float* biW  = (const float*)d_in[13];
    const float* bib  = (const float*)d_in[14];
    float* outp = (float*)d_out;

    float* egoA = (float*)d_ws;                        // NN*32 f32
    float* egoB = egoA + (size_t)NN * 32;              // NN*32 f32
    uint2* recs = (uint2*)(egoB + (size_t)NN * 32);    // NE uint2
    int*   cnt  = (int*)(recs + (size_t)NE);           // NN
    int*   rp   = cnt + NN;                            // NN+1
    int*   cur  = rp + NN + 1;                         // NN
    int*   bsum = cur + NN;                            // 256

    const size_t need = (size_t)(bsum + 256) - (size_t)d_ws;
    const bool csr_ok = ws_size >= need;

    copy_emb_kernel<<<(NN * 4 + 255) / 256, 256, 0, stream>>>(uemb, iemb, egoA, outp);
    mlp_kernel<<<782, 512, 0, stream>>>(une, ueW1, ueW2, egoA, outp, NU, 0);
    mlp_kernel<<<782, 512, 0, stream>>>(se, ieW1, ieW2, egoA, outp, NI, NU);

    if (csr_ok) {
        const int NBLK = (NN + 1023) / 1024;  // 196
        hipMemsetAsync(cnt, 0, (size_t)NN * sizeof(int), stream);
        count_ranged_kernel<<<NRANGE * NBJ, 256, 0, stream>>>(erow, cnt);
        scan_blk_kernel<<<NBLK, 256, 0, stream>>>(cnt, rp, bsum);
        scan_bsum_kernel<<<1, 256, 0, stream>>>(bsum, NBLK);
        add_off_kernel<<<(NN + 255) / 256, 256, 0, stream>>>(rp, bsum, cur);
        fill_ranged_kernel<<<NRANGE * NBJ, 256, 0, stream>>>(erow, ecol, evalp, cur, recs);

        const float* egoIn = egoA;
        float* egoOut = egoB;
        for (int l = 0; l < 3; ++l) {
            pull_update_kernel<<<NN / 8, 256, 0, stream>>>(rp, recs, egoIn, egoOut, outp,
                                                           gcW, gcb, biW, bib, l);
            const float* t = egoOut; egoOut = (float*)egoIn; egoIn = t;
        }
    } else {
        float* side = egoB;
        for (int l = 0; l < 3; ++l) {
            hipMemsetAsync(side, 0, (size_t)NN * 32 * sizeof(float), stream);
            scatter_kernel<<<(NE * 8 + 255) / 256, 256, 0, stream>>>(erow, ecol, evalp, egoA, side);
            update_kernel<<<(NN + 255) / 256, 256, 0, stream>>>(side, egoA, outp,
                                                                gcW, gcb, biW, bib, l);
        }
    }
}

// Round 4
// 834.499 us; speedup vs baseline: 1.8194x; 1.8194x over previous
//
#include <hip/hip_runtime.h>
#include <cstdint>

#define NU 100000
#define NI 100000
#define NN 200000
#define NE 3200000
#define TXT 768
#define DD 32
#define NRANGE 8
#define ROWS_PER_RANGE (NN / NRANGE)   // 25000
#define NBJ 313        // blocks per range for ranged kernels

typedef _Float16 f16x8 __attribute__((ext_vector_type(8)));
typedef _Float16 f16x4 __attribute__((ext_vector_type(4)));
typedef float    f32x4 __attribute__((ext_vector_type(4)));

__device__ __forceinline__ float lrelu(float x) { return x >= 0.f ? x : 0.01f * x; }

// ---------------------------------------------------------------------------
// Copy pretrained 16-dim embeddings into ego[:,0:16] and out[:,0:16]
// ---------------------------------------------------------------------------
__global__ void copy_emb_kernel(const float* __restrict__ uemb,
                                const float* __restrict__ iemb,
                                float* __restrict__ ego,
                                float* __restrict__ outp)
{
    int idx = blockIdx.x * blockDim.x + threadIdx.x;
    if (idx >= NN * 4) return;
    int n = idx >> 2, q = idx & 3;
    float4 v;
    if (n < NU) v = ((const float4*)uemb)[(size_t)n * 4 + q];
    else        v = ((const float4*)iemb)[(size_t)(n - NU) * 4 + q];
    ((float4*)ego)[(size_t)n * 8 + q]   = v;
    ((float4*)outp)[(size_t)n * 32 + q] = v;
}

// ---------------------------------------------------------------------------
// MFMA MLP: created = relu(X @ W1) @ W2 ; writes ego[:,16:32], out[:,16:32].
// One wave per 16-row tile. W1 staged f16 in LDS in MFMA-slot-linear order
// (ds_read_b128, contiguous per lane). Both matmuls on the matrix pipe;
// h goes through a per-wave LDS transpose (row-major, stride 40 halves).
// k-packing: slot (lane,j) -> k = (lane>>4)*8+j, used consistently for A and
// B => correct for any HW k-map (slot-slot pairing is the only invariant).
// ---------------------------------------------------------------------------
__global__ __launch_bounds__(512) void mlp_mfma_kernel(
    const float* __restrict__ X,    // 100000 x 768
    const float* __restrict__ W1,   // 768 x 32
    const float* __restrict__ W2,   // 32 x 16
    float* __restrict__ ego,
    float* __restrict__ outp,
    int node_base)
{
    __shared__ _Float16 W1s[24576];      // 48 KB: [kb(24)][half(2)][lane(64)][j(8)]
    __shared__ _Float16 hbuf[8][640];    // per-wave 16 x 40 (h, row-major, padded)

    const int tid  = threadIdx.x;
    const int lane = tid & 63;
    const int wv   = tid >> 6;

    // stage W1 (f32 -> f16) into slot-linear layout
    for (int i = tid; i < 24576; i += 512) {
        int j   = i & 7;
        int ln  = (i >> 3) & 63;
        int kbH = i >> 9;
        int kb  = kbH >> 1, H = kbH & 1;
        int k   = kb * 32 + (ln >> 4) * 8 + j;
        int c   = H * 16 + (ln & 15);
        W1s[i] = (_Float16)W1[k * 32 + c];
    }

    // W2 B-fragment in registers: slot (lane,j) = W2[(lane>>4)*8+j][lane&15]
    f16x8 bw2;
    #pragma unroll
    for (int j = 0; j < 8; ++j)
        bw2[j] = (_Float16)W2[((lane >> 4) * 8 + j) * 16 + (lane & 15)];

    __syncthreads();

    _Float16* hb = &hbuf[wv][0];
    const int gw = blockIdx.x * 8 + wv;                 // 0..4095 (512 blocks)
    const int t0 = (int)(((long)gw * 6250) >> 12);      // balanced tile ranges
    const int t1 = (int)(((long)(gw + 1) * 6250) >> 12);

    for (int tile = t0; tile < t1; ++tile) {
        const float* xp = X + (size_t)(tile * 16 + (lane & 15)) * TXT + (lane >> 4) * 8;
        f32x4 c0 = {0.f, 0.f, 0.f, 0.f};
        f32x4 c1 = {0.f, 0.f, 0.f, 0.f};

        #pragma unroll 4
        for (int kb = 0; kb < 24; ++kb) {
            float4 xa = *(const float4*)(xp + kb * 32);
            float4 xb = *(const float4*)(xp + kb * 32 + 4);
            f16x8 a;
            a[0] = (_Float16)xa.x; a[1] = (_Float16)xa.y;
            a[2] = (_Float16)xa.z; a[3] = (_Float16)xa.w;
            a[4] = (_Float16)xb.x; a[5] = (_Float16)xb.y;
            a[6] = (_Float16)xb.z; a[7] = (_Float16)xb.w;
            f16x8 b0 = *(const f16x8*)&W1s[(kb * 2 + 0) * 512 + lane * 8];
            f16x8 b1 = *(const f16x8*)&W1s[(kb * 2 + 1) * 512 + lane * 8];
            c0 = __builtin_amdgcn_mfma_f32_16x16x32_f16(a, b0, c0, 0, 0, 0);
            c1 = __builtin_amdgcn_mfma_f32_16x16x32_f16(a, b1, c1, 0, 0, 0);
        }

        // h = relu(c): C layout col=lane&15, row=(lane>>4)*4+j. Write row-major h.
        #pragma unroll
        for (int j = 0; j < 4; ++j) {
            int r = (lane >> 4) * 4 + j;
            hb[r * 40 + (lane & 15)]      = (_Float16)fmaxf(c0[j], 0.f);
            hb[r * 40 + (lane & 15) + 16] = (_Float16)fmaxf(c1[j], 0.f);
        }
        // A2 fragment: slot (lane,j) = h[lane&15][(lane>>4)*8+j] (contiguous b64 x2)
        const _Float16* ap = &hb[(lane & 15) * 40 + (lane >> 4) * 8];
        f16x4 lo = *(const f16x4*)ap;
        f16x4 hi = *(const f16x4*)(ap + 4);
        f16x8 a2;
        a2[0] = lo[0]; a2[1] = lo[1]; a2[2] = lo[2]; a2[3] = lo[3];
        a2[4] = hi[0]; a2[5] = hi[1]; a2[6] = hi[2]; a2[7] = hi[3];

        f32x4 c2 = {0.f, 0.f, 0.f, 0.f};
        c2 = __builtin_amdgcn_mfma_f32_16x16x32_f16(a2, bw2, c2, 0, 0, 0);

        // out col = lane&15, rows (lane>>4)*4+j
        const int rbase = node_base + tile * 16 + (lane >> 4) * 4;
        const int j2 = lane & 15;
        #pragma unroll
        for (int j = 0; j < 4; ++j) {
            float v = c2[j];
            ego [(size_t)(rbase + j) * 32  + 16 + j2] = v;
            outp[(size_t)(rbase + j) * 128 + 16 + j2] = v;
        }
    }
}

// ---------------------------------------------------------------------------
// XCD-range-partitioned CSR build (block b&7 owns a row range -> L2-local)
// ---------------------------------------------------------------------------
__global__ __launch_bounds__(256) void count_ranged_kernel(const int* __restrict__ erow,
                                                           int* __restrict__ cnt)
{
    const int rlo = (blockIdx.x & 7) * ROWS_PER_RANGE;
    const int rhi = rlo + ROWS_PER_RANGE;
    const int bj  = blockIdx.x >> 3;
    const int4* e4 = (const int4*)erow;
    for (int c = bj * 256 + threadIdx.x; c < NE / 4; c += NBJ * 256) {
        int4 v = e4[c];
        if (v.x >= rlo && v.x < rhi) atomicAdd(&cnt[v.x], 1);
        if (v.y >= rlo && v.y < rhi) atomicAdd(&cnt[v.y], 1);
        if (v.z >= rlo && v.z < rhi) atomicAdd(&cnt[v.z], 1);
        if (v.w >= rlo && v.w < rhi) atomicAdd(&cnt[v.w], 1);
    }
}

__global__ __launch_bounds__(256) void scan_blk_kernel(const int* __restrict__ cnt,
                                                       int* __restrict__ rp,
                                                       int* __restrict__ bsum)
{
    __shared__ int ts[256];
    const int tid = threadIdx.x;
    const int base = blockIdx.x * 1024 + tid * 4;
    int v0 = (base + 0 < NN) ? cnt[base + 0] : 0;
    int v1 = (base + 1 < NN) ? cnt[base + 1] : 0;
    int v2 = (base + 2 < NN) ? cnt[base + 2] : 0;
    int v3 = (base + 3 < NN) ? cnt[base + 3] : 0;
    int s = v0 + v1 + v2 + v3;
    ts[tid] = s;
    __syncthreads();
    for (int off = 1; off < 256; off <<= 1) {
        int t = (tid >= off) ? ts[tid - off] : 0;
        __syncthreads();
        ts[tid] += t;
        __syncthreads();
    }
    int excl = ts[tid] - s;
    if (base + 0 < NN) rp[base + 0] = excl;
    if (base + 1 < NN) rp[base + 1] = excl + v0;
    if (base + 2 < NN) rp[base + 2] = excl + v0 + v1;
    if (base + 3 < NN) rp[base + 3] = excl + v0 + v1 + v2;
    if (tid == 255) bsum[blockIdx.x] = ts[255];
}

__global__ __launch_bounds__(256) void scan_bsum_kernel(int* __restrict__ bsum, int nblk)
{
    __shared__ int ts[256];
    const int tid = threadIdx.x;
    int v = (tid < nblk) ? bsum[tid] : 0;
    ts[tid] = v;
    __syncthreads();
    for (int off = 1; off < 256; off <<= 1) {
        int t = (tid >= off) ? ts[tid - off] : 0;
        __syncthreads();
        ts[tid] += t;
        __syncthreads();
    }
    if (tid < nblk) bsum[tid] = ts[tid] - v;
}

__global__ __launch_bounds__(256) void add_off_kernel(int* __restrict__ rp,
                                                      const int* __restrict__ bsum,
                                                      int* __restrict__ cur)
{
    int i = blockIdx.x * 256 + threadIdx.x;
    if (i < NN) {
        int v = rp[i] + bsum[i >> 10];
        rp[i] = v;
        cur[i] = v;
    }
    if (i == 0) rp[NN] = NE;
}

__global__ __launch_bounds__(256) void fill_ranged_kernel(const int* __restrict__ erow,
                                                          const int* __restrict__ ecol,
                                                          const float* __restrict__ eval,
                                                          int* __restrict__ cur,
                                                          uint2* __restrict__ recs)
{
    const int rlo = (blockIdx.x & 7) * ROWS_PER_RANGE;
    const int rhi = rlo + ROWS_PER_RANGE;
    const int bj  = blockIdx.x >> 3;
    const int4* e4 = (const int4*)erow;
    for (int c = bj * 256 + threadIdx.x; c < NE / 4; c += NBJ * 256) {
        int4 v = e4[c];
        int base = c * 4;
        if (v.x >= rlo && v.x < rhi) {
            int pos = atomicAdd(&cur[v.x], 1);
            recs[pos] = make_uint2((unsigned)ecol[base+0], __float_as_uint(eval[base+0]));
        }
        if (v.y >= rlo && v.y < rhi) {
            int pos = atomicAdd(&cur[v.y], 1);
            recs[pos] = make_uint2((unsigned)ecol[base+1], __float_as_uint(eval[base+1]));
        }
        if (v.z >= rlo && v.z < rhi) {
            int pos = atomicAdd(&cur[v.z], 1);
            recs[pos] = make_uint2((unsigned)ecol[base+2], __float_as_uint(eval[base+2]));
        }
        if (v.w >= rlo && v.w < rhi) {
            int pos = atomicAdd(&cur[v.w], 1);
            recs[pos] = make_uint2((unsigned)ecol[base+3], __float_as_uint(eval[base+3]));
        }
    }
}

// ---------------------------------------------------------------------------
// Pull aggregation: one wave per row; 8 edge-slots x 8 dim-lanes; no atomics.
// ---------------------------------------------------------------------------
__global__ __launch_bounds__(256) void pull_kernel(
    const int* __restrict__ rp, const uint2* __restrict__ recs,
    const float* __restrict__ ego, float* __restrict__ side)
{
    const int w    = blockIdx.x * 4 + (threadIdx.x >> 6);   // row
    const int lane = threadIdx.x & 63;
    const int slot = lane >> 3;   // edge slot 0..7
    const int q    = lane & 7;    // float4 index 0..7
    const int start = rp[w], end = rp[w + 1];

    float4 acc = make_float4(0.f, 0.f, 0.f, 0.f);
    for (int e = start + slot; e < end; e += 8) {
        uint2 rec = recs[e];
        float a = __uint_as_float(rec.y);
        float4 v = ((const float4*)ego)[(size_t)rec.x * 8 + q];
        acc.x += a * v.x; acc.y += a * v.y; acc.z += a * v.z; acc.w += a * v.w;
    }
    #pragma unroll
    for (int m = 8; m <= 32; m <<= 1) {
        acc.x += __shfl_xor(acc.x, m, 64);
        acc.y += __shfl_xor(acc.y, m, 64);
        acc.z += __shfl_xor(acc.z, m, 64);
        acc.w += __shfl_xor(acc.w, m, 64);
    }
    if (slot == 0)
        ((float4*)side)[(size_t)w * 8 + q] = acc;
}

// ---------------------------------------------------------------------------
// ego = lrelu(side@gcW + gcb) + lrelu((ego*side)@biW + bib); out = normalize
// ---------------------------------------------------------------------------
__global__ __launch_bounds__(256) void update_kernel(
    const float* __restrict__ side, float* __restrict__ ego,
    float* __restrict__ outp,
    const float* __restrict__ gcW, const float* __restrict__ gcb,
    const float* __restrict__ biW, const float* __restrict__ bib, int l)
{
    int n = blockIdx.x * 256 + threadIdx.x;
    if (n >= NN) return;

    float s[32], e[32];
    const float4* s4 = (const float4*)side + (size_t)n * 8;
    const float4* e4 = (const float4*)ego  + (size_t)n * 8;
    #pragma unroll
    for (int q = 0; q < 8; ++q) {
        float4 v = s4[q];
        s[q*4+0]=v.x; s[q*4+1]=v.y; s[q*4+2]=v.z; s[q*4+3]=v.w;
        float4 w = e4[q];
        e[q*4+0]=w.x; e[q*4+1]=w.y; e[q*4+2]=w.z; e[q*4+3]=w.w;
    }
    #pragma unroll
    for (int k = 0; k < 32; ++k) e[k] *= s[k];

    const float* Wg = gcW + (size_t)l * 1024;
    const float* Wb = biW + (size_t)l * 1024;

    float A[32];
    #pragma unroll
    for (int j = 0; j < 32; ++j) A[j] = gcb[l * 32 + j];
    #pragma unroll 4
    for (int k = 0; k < 32; ++k) {
        float sk = s[k];
        #pragma unroll
        for (int j = 0; j < 32; ++j) A[j] += sk * Wg[k * 32 + j];
    }
    #pragma unroll
    for (int j = 0; j < 32; ++j) A[j] = lrelu(A[j]);

    float B[32];
    #pragma unroll
    for (int j = 0; j < 32; ++j) B[j] = bib[l * 32 + j];
    #pragma unroll 4
    for (int k = 0; k < 32; ++k) {
        float pk = e[k];
        #pragma unroll
        for (int j = 0; j < 32; ++j) B[j] += pk * Wb[k * 32 + j];
    }

    float ss = 0.f;
    #pragma unroll
    for (int j = 0; j < 32; ++j) {
        float v = A[j] + lrelu(B[j]);
        A[j] = v;
        ss += v * v;
    }
    float inv = 1.0f / fmaxf(sqrtf(ss), 1e-12f);

    float4* egod = (float4*)(ego + (size_t)n * 32);
    float4* outd = (float4*)(outp + (size_t)n * 128 + (size_t)(l + 1) * 32);
    #pragma unroll
    for (int q = 0; q < 8; ++q) {
        float4 v = make_float4(A[q*4+0], A[q*4+1], A[q*4+2], A[q*4+3]);
        egod[q] = v;
        float4 w = make_float4(v.x*inv, v.y*inv, v.z*inv, v.w*inv);
        outd[q] = w;
    }
}

// ---------------------------------------------------------------------------
// Legacy fallback scatter (only if workspace too small for CSR)
// ---------------------------------------------------------------------------
__global__ __launch_bounds__(256) void scatter_kernel(
    const int* __restrict__ erow, const int* __restrict__ ecol,
    const float* __restrict__ eval, const float* __restrict__ ego,
    float* __restrict__ side)
{
    int i = blockIdx.x * 256 + threadIdx.x;
    if (i >= NE * 8) return;
    int e = i >> 3, q = i & 7;
    int rI = erow[e];
    int c  = ecol[e];
    float a = eval[e];
    float4 v = ((const float4*)ego)[(size_t)c * 8 + q];
    float* dst = side + (size_t)rI * 32 + q * 4;
    atomicAdd(dst + 0, a * v.x);
    atomicAdd(dst + 1, a * v.y);
    atomicAdd(dst + 2, a * v.z);
    atomicAdd(dst + 3, a * v.w);
}

// ---------------------------------------------------------------------------
extern "C" void kernel_launch(void* const* d_in, const int* in_sizes, int n_in,
                              void* d_out, int out_size, void* d_ws, size_t ws_size,
                              hipStream_t stream)
{
    const int*   erow = (const int*)d_in[0];
    const int*   ecol = (const int*)d_in[1];
    const float* evalp = (const float*)d_in[2];
    const float* une  = (const float*)d_in[3];
    const float* se   = (const float*)d_in[4];
    const float* uemb = (const float*)d_in[5];
    const float* iemb = (const float*)d_in[6];
    const float* ueW1 = (const float*)d_in[7];
    const float* ueW2 = (const float*)d_in[8];
    const float* ieW1 = (const float*)d_in[9];
    const float* ieW2 = (const float*)d_in[10];
    const float* gcW  = (const float*)d_in[11];
    const float* gcb  = (const float*)d_in[12];
    const float* biW  = (const float*)d_in[13];
    const float* bib  = (const float*)d_in[14];
    float* outp = (float*)d_out;

    float* ego  = (float*)d_ws;                        // NN*32 f32
    float* side = ego + (size_t)NN * 32;               // NN*32 f32
    uint2* recs = (uint2*)(side + (size_t)NN * 32);    // NE uint2
    int*   cnt  = (int*)(recs + (size_t)NE);           // NN
    int*   rp   = cnt + NN;                            // NN+1
    int*   cur  = rp + NN + 1;                         // NN
    int*   bsum = cur + NN;                            // 256

    const size_t need = (size_t)(bsum + 256) - (size_t)d_ws;
    const bool csr_ok = ws_size >= need;

    copy_emb_kernel<<<(NN * 4 + 255) / 256, 256, 0, stream>>>(uemb, iemb, ego, outp);
    mlp_mfma_kernel<<<512, 512, 0, stream>>>(une, ueW1, ueW2, ego, outp, 0);
    mlp_mfma_kernel<<<512, 512, 0, stream>>>(se, ieW1, ieW2, ego, outp, NU);

    if (csr_ok) {
        const int NBLK = (NN + 1023) / 1024;  // 196
        hipMemsetAsync(cnt, 0, (size_t)NN * sizeof(int), stream);
        count_ranged_kernel<<<NRANGE * NBJ, 256, 0, stream>>>(erow, cnt);
        scan_blk_kernel<<<NBLK, 256, 0, stream>>>(cnt, rp, bsum);
        scan_bsum_kernel<<<1, 256, 0, stream>>>(bsum, NBLK);
        add_off_kernel<<<(NN + 255) / 256, 256, 0, stream>>>(rp, bsum, cur);
        fill_ranged_kernel<<<NRANGE * NBJ, 256, 0, stream>>>(erow, ecol, evalp, cur, recs);

        for (int l = 0; l < 3; ++l) {
            pull_kernel<<<NN / 4, 256, 0, stream>>>(rp, recs, ego, side);
            update_kernel<<<(NN + 255) / 256, 256, 0, stream>>>(side, ego, outp,
                                                                gcW, gcb, biW, bib, l);
        }
    } else {
        for (int l = 0; l < 3; ++l) {
            hipMemsetAsync(side, 0, (size_t)NN * 32 * sizeof(float), stream);
            scatter_kernel<<<(NE * 8 + 255) / 256, 256, 0, stream>>>(erow, ecol, evalp, ego, side);
            update_kernel<<<(NN + 255) / 256, 256, 0, stream>>>(side, ego, outp,
                                                                gcW, gcb, biW, bib, l);
        }
    }
}